// Round 3
// baseline (3759.615 us; speedup 1.0000x reference)
//
#include <hip/hip_runtime.h>

#define DIM 64
#define HID 256
#define NSTEPS 100
#define DT (1.0f / 100.0f)

typedef __attribute__((ext_vector_type(8))) short short8;   // 8 bf16 (MFMA A/B frag)
typedef __attribute__((ext_vector_type(4))) float floatx4;  // MFMA C/D frag

__device__ __forceinline__ unsigned short f2bf(float f) {
  union { float f; unsigned int u; } v; v.f = f;
  unsigned int u = v.u;
  return (unsigned short)((u + 0x7fffu + ((u >> 16) & 1u)) >> 16);  // RNE
}
__device__ __forceinline__ unsigned int pack2(float a, float b) {
  return (unsigned int)f2bf(a) | ((unsigned int)f2bf(b) << 16);
}
__device__ __forceinline__ float fast_tanh(float x) {
  float e = __expf(2.0f * x);
  return 1.0f - 2.0f * __builtin_amdgcn_rcpf(e + 1.0f);
}

// Repack W (K x N row-major fp32) into frag-major bf16.
// element ((s*ntiles + t)*64 + lane)*8 + j  holds  W[k = s*32+(lane>>4)*8+j][n = t*16+(lane&15)]
// == B-frag of W == A-frag of W^T (same lane->element map with m<->n swapped).
__global__ void prep_weights(const float* __restrict__ W1,
                             const float* __restrict__ W2,
                             const float* __restrict__ W3,
                             unsigned short* __restrict__ ws) {
  int e = blockIdx.x * 256 + threadIdx.x;  // 98304 total
  const float* src; int N, ntile, el, base;
  if (e < 16384)      { src = W1; N = 256; ntile = 16; base = 0;     el = e; }
  else if (e < 81920) { src = W2; N = 256; ntile = 16; base = 16384; el = e - 16384; }
  else                { src = W3; N = 64;  ntile = 4;  base = 81920; el = e - 81920; }
  int j = el & 7;
  int l = (el >> 3) & 63;
  int rem = el >> 9;
  int t = rem % ntile;
  int s = rem / ntile;
  int k = s * 32 + ((l >> 4) << 3) + j;
  int n = t * 16 + (l & 15);
  ws[base + el] = f2bf(src[k * N + n]);
}

// Transposed frame: M = features (weights = A operand, register-resident),
// N = batch (activations = B operand, stored transposed [n][k] in LDS).
// 512 threads = 8 waves, 1 block/CU. Wave w:
//   L1/L2: M-tiles {2w, 2w+1}, all 4 N-tiles.
//   L3/RK4: M-tile (w&3), N-tiles {2*(w>>2), 2*(w>>2)+1}.
// C-layout (col=batch=lane&15, row=feature=q*4+r) -> lane holds 4 consecutive
// features of one batch row -> packed b64 LDS writes, b128 reads. No scalar b16.
__global__ __launch_bounds__(512, 2)
void cnf_kernel(const float* __restrict__ z0,
                const float* __restrict__ b1,
                const float* __restrict__ b2,
                const float* __restrict__ b3,
                const unsigned short* __restrict__ wsAll,
                float* __restrict__ out) {
  constexpr int LDZ = 72;   // shorts; 144 B row stride (16B-aligned)
  constexpr int LDH = 264;  // shorts; 528 B row stride (16B-aligned)
  __shared__ __align__(16) unsigned short Zbuf[64 * LDZ];   // Z^T [n][k]  9216 B
  __shared__ __align__(16) unsigned short Hbuf[64 * LDH];   // H^T [n][k] 33792 B

  const int tid  = threadIdx.x;
  const int wave = tid >> 6;
  const int lane = tid & 63;
  const int i15  = lane & 15;   // batch col within N-tile
  const int q    = lane >> 4;
  const int q8   = q * 8;
  const int grow = blockIdx.x * 64;
  const int mt3  = wave & 3;    // L3 M-tile
  const int ntp  = wave >> 2;   // L3 N-pair

  const unsigned short* wsW1 = wsAll;
  const unsigned short* wsW2 = wsAll + 16384;
  const unsigned short* wsW3 = wsAll + 81920;

  // ---- register-resident weight A-frags ----
  short8 w1f[2][2], w2f[8][2], w3f[8];
#pragma unroll
  for (int s = 0; s < 2; ++s)
#pragma unroll
    for (int tt = 0; tt < 2; ++tt)
      w1f[s][tt] = *(const short8*)&wsW1[((s * 16 + 2 * wave + tt) * 64 + lane) * 8];
#pragma unroll
  for (int s = 0; s < 8; ++s)
#pragma unroll
    for (int tt = 0; tt < 2; ++tt)
      w2f[s][tt] = *(const short8*)&wsW2[((s * 16 + 2 * wave + tt) * 64 + lane) * 8];
#pragma unroll
  for (int s = 0; s < 8; ++s)
    w3f[s] = *(const short8*)&wsW3[((s * 4 + mt3) * 64 + lane) * 8];

  // ---- biases per-row (feature = row = q*4+r) ----
  float b1a[2][4], b2a[2][4], b3a[4];
#pragma unroll
  for (int tt = 0; tt < 2; ++tt) {
    *(float4*)b1a[tt] = *(const float4*)&b1[(2 * wave + tt) * 16 + q * 4];
    *(float4*)b2a[tt] = *(const float4*)&b2[(2 * wave + tt) * 16 + q * 4];
  }
  *(float4*)b3a = *(const float4*)&b3[mt3 * 16 + q * 4];

  // ---- RK4 state: lane holds features mt3*16+q*4..+3 of batch rows nt*16+i15 ----
  float z[8], zacc[8];
#pragma unroll
  for (int j = 0; j < 2; ++j) {
    const int nt = 2 * ntp + j;
    float4 v = *(const float4*)&z0[(grow + nt * 16 + i15) * DIM + mt3 * 16 + q * 4];
    z[j * 4 + 0] = v.x; z[j * 4 + 1] = v.y; z[j * 4 + 2] = v.z; z[j * 4 + 3] = v.w;
#pragma unroll
    for (int r = 0; r < 4; ++r) zacc[j * 4 + r] = 0.f;
    uint2 p; p.x = pack2(v.x, v.y); p.y = pack2(v.z, v.w);
    *(uint2*)&Zbuf[(nt * 16 + i15) * LDZ + mt3 * 16 + q * 4] = p;
  }

  const float DT6 = DT / 6.0f, DT3 = DT / 3.0f, DTH = 0.5f * DT;

#pragma unroll 1
  for (int it = 0; it < NSTEPS * 4; ++it) {
    const int st = it & 3;
    __syncthreads();  // B1: Zbuf stage visible; all L3 reads of prev H2 done

    // ---- Layer 1: K=64 ----
    floatx4 acc[2][4];
#pragma unroll
    for (int tt = 0; tt < 2; ++tt)
#pragma unroll
      for (int nt = 0; nt < 4; ++nt) acc[tt][nt] = floatx4{0.f, 0.f, 0.f, 0.f};
#pragma unroll
    for (int nt = 0; nt < 4; ++nt)
#pragma unroll
      for (int s = 0; s < 2; ++s) {
        short8 bz = *(const short8*)&Zbuf[(nt * 16 + i15) * LDZ + s * 32 + q8];
        acc[0][nt] = __builtin_amdgcn_mfma_f32_16x16x32_bf16(w1f[s][0], bz, acc[0][nt], 0, 0, 0);
        acc[1][nt] = __builtin_amdgcn_mfma_f32_16x16x32_bf16(w1f[s][1], bz, acc[1][nt], 0, 0, 0);
      }
#pragma unroll
    for (int tt = 0; tt < 2; ++tt)
#pragma unroll
      for (int nt = 0; nt < 4; ++nt) {
        float h0 = fast_tanh(acc[tt][nt][0] + b1a[tt][0]);
        float h1 = fast_tanh(acc[tt][nt][1] + b1a[tt][1]);
        float h2 = fast_tanh(acc[tt][nt][2] + b1a[tt][2]);
        float h3 = fast_tanh(acc[tt][nt][3] + b1a[tt][3]);
        uint2 p; p.x = pack2(h0, h1); p.y = pack2(h2, h3);
        *(uint2*)&Hbuf[(nt * 16 + i15) * LDH + (2 * wave + tt) * 16 + q * 4] = p;
      }
    __syncthreads();  // B2: H1 visible

    // ---- Layer 2: K=256 ----
    floatx4 acc2[2][4];
#pragma unroll
    for (int tt = 0; tt < 2; ++tt)
#pragma unroll
      for (int nt = 0; nt < 4; ++nt) acc2[tt][nt] = floatx4{0.f, 0.f, 0.f, 0.f};
#pragma unroll
    for (int nt = 0; nt < 4; ++nt)
#pragma unroll
      for (int s = 0; s < 8; ++s) {
        short8 bh = *(const short8*)&Hbuf[(nt * 16 + i15) * LDH + s * 32 + q8];
        acc2[0][nt] = __builtin_amdgcn_mfma_f32_16x16x32_bf16(w2f[s][0], bh, acc2[0][nt], 0, 0, 0);
        acc2[1][nt] = __builtin_amdgcn_mfma_f32_16x16x32_bf16(w2f[s][1], bh, acc2[1][nt], 0, 0, 0);
      }
    __syncthreads();  // B3: all H1 reads done -> Hbuf may be overwritten

#pragma unroll
    for (int tt = 0; tt < 2; ++tt)
#pragma unroll
      for (int nt = 0; nt < 4; ++nt) {
        float h0 = fast_tanh(acc2[tt][nt][0] + b2a[tt][0]);
        float h1 = fast_tanh(acc2[tt][nt][1] + b2a[tt][1]);
        float h2 = fast_tanh(acc2[tt][nt][2] + b2a[tt][2]);
        float h3 = fast_tanh(acc2[tt][nt][3] + b2a[tt][3]);
        uint2 p; p.x = pack2(h0, h1); p.y = pack2(h2, h3);
        *(uint2*)&Hbuf[(nt * 16 + i15) * LDH + (2 * wave + tt) * 16 + q * 4] = p;
      }
    __syncthreads();  // B4: H2 visible

    // ---- Layer 3 + RK4 ----
    floatx4 a3[2];
    a3[0] = floatx4{0.f, 0.f, 0.f, 0.f};
    a3[1] = floatx4{0.f, 0.f, 0.f, 0.f};
#pragma unroll
    for (int j = 0; j < 2; ++j) {
      const int nt = 2 * ntp + j;
#pragma unroll
      for (int s = 0; s < 8; ++s) {
        short8 bh = *(const short8*)&Hbuf[(nt * 16 + i15) * LDH + s * 32 + q8];
        a3[j] = __builtin_amdgcn_mfma_f32_16x16x32_bf16(w3f[s], bh, a3[j], 0, 0, 0);
      }
    }
    const float wsum  = (st == 0 || st == 3) ? DT6 : DT3;
    const float cst   = (st == 2) ? DT : DTH;
    const bool  last  = (st == 3);
    const bool  first = (st == 0);
#pragma unroll
    for (int j = 0; j < 2; ++j) {
      const int nt = 2 * ntp + j;
      float stg[4];
#pragma unroll
      for (int r = 0; r < 4; ++r) {
        const int i = j * 4 + r;
        float k = a3[j][r] + b3a[r];
        float za = first ? z[i] : zacc[i];
        za += wsum * k;
        zacc[i] = za;
        if (last) { z[i] = za; stg[r] = za; }
        else      { stg[r] = z[i] + cst * k; }
      }
      uint2 p; p.x = pack2(stg[0], stg[1]); p.y = pack2(stg[2], stg[3]);
      *(uint2*)&Zbuf[(nt * 16 + i15) * LDZ + mt3 * 16 + q * 4] = p;
    }
  }

  // ---- final store ----
#pragma unroll
  for (int j = 0; j < 2; ++j) {
    const int nt = 2 * ntp + j;
    float4 v;
    v.x = z[j * 4 + 0]; v.y = z[j * 4 + 1]; v.z = z[j * 4 + 2]; v.w = z[j * 4 + 3];
    *(float4*)&out[(grow + nt * 16 + i15) * DIM + mt3 * 16 + q * 4] = v;
  }
}

extern "C" void kernel_launch(void* const* d_in, const int* in_sizes, int n_in,
                              void* d_out, int out_size, void* d_ws, size_t ws_size,
                              hipStream_t stream) {
  const float* z0 = (const float*)d_in[0];
  const float* W1 = (const float*)d_in[1];
  const float* b1 = (const float*)d_in[2];
  const float* W2 = (const float*)d_in[3];
  const float* b2 = (const float*)d_in[4];
  const float* W3 = (const float*)d_in[5];
  const float* b3 = (const float*)d_in[6];
  unsigned short* ws = (unsigned short*)d_ws;  // 98304 bf16 = 196608 B

  prep_weights<<<384, 256, 0, stream>>>(W1, W2, W3, ws);
  cnf_kernel<<<512, 512, 0, stream>>>(z0, b1, b2, b3, ws, (float*)d_out);
}